// Round 4
// baseline (1533.029 us; speedup 1.0000x reference)
//
#include <hip/hip_runtime.h>
#include <math.h>

#define T_ 512
#define D_ 512
#define H_ 8
#define N_ 64
#define A_ 65
#define HN_ 512
#define HA_ 520
#define ST_ (T_*A_)       // per-head stride in Q/K/V (no padding)
#define EPS_ 1e-6
#define TINY_ 1e-15
#define IT 8
#define PTT 8
#define CTT 8

__device__ __forceinline__ double wsumd(double v){
#pragma unroll
  for (int o=32;o;o>>=1) v += __shfl_xor(v,o);
  return v;
}
__device__ __forceinline__ double wmaxd(double v){
#pragma unroll
  for (int o=32;o;o>>=1) v = fmax(v,__shfl_xor(v,o));
  return v;
}

__global__ void k_fill(float* __restrict__ out, float val){
  int i = blockIdx.x*256 + threadIdx.x;
  if (i < T_*D_) out[i] = val;
}

// ---------------- kernel 1: u = x @ W + b (double accumulate)
template<typename S>
__global__ __launch_bounds__(256) void k_projD(
    const float* __restrict__ x, const float* __restrict__ W,
    const float* __restrict__ b, S* __restrict__ u){
  int c  = blockIdx.x*256 + threadIdx.x;
  int t0 = blockIdx.y*PTT;
  double acc[PTT];
#pragma unroll
  for (int i=0;i<PTT;i++) acc[i]=0.0;
  for (int d=0; d<D_; d++){
    double w = (double)W[d*HN_ + c];
#pragma unroll
    for (int i=0;i<PTT;i++) acc[i] = fma((double)x[(t0+i)*D_ + d], w, acc[i]);
  }
  double bias = (double)b[c];
#pragma unroll
  for (int i=0;i<PTT;i++) u[(t0+i)*HN_ + c] = (S)(acc[i] + bias);
}

// ---------------- kernel 2: optional rope (f64 trig), then lift (literal f64)
template<typename S>
__global__ __launch_bounds__(64) void k_liftD(
    const S* __restrict__ u, S* __restrict__ P, int do_rope){
  int bid = blockIdx.x;
  int h = bid & 7, t = bid >> 3, n = threadIdx.x;
  double v = (double)u[t*HN_ + h*N_ + n];
  if (do_rope){
    int fi = n & 31;
    double inv_f = 1.0 / pow(10000.0, (double)(2*fi)*(1.0/64.0));
    double ang = (double)t * inv_f;
    double cs = cos(ang), sn = sin(ang);
    double vp = __shfl_xor(v, 32);
    double rot = (n<32) ? -vp : vp;
    v = v*cs + rot*sn;
  }
  // exp_map(o=[1,0..], [0,v]): mink = sum v^2
  double ss = wsumd(v*v);
  double vn = sqrt(fmax(ss, TINY_));
  double ch = cosh(vn);
  double s  = sinh(vn)/fmax(vn, TINY_);
  double y  = s*v;
  // project
  double xx = wsumd(y*y) - ch*ch;
  double scale = sqrt(fmax(fabs(xx), TINY_));
  S* o = P + h*ST_ + t*A_;
  if (n==0) o[0] = (S)fabs(ch/scale);
  o[n+1] = (S)(y/scale);
}

// ---------------- kernel 3: attention core, fully literal, all double
template<typename S>
__global__ __launch_bounds__(256) void k_attnD(
    const S* __restrict__ Q, const S* __restrict__ K, const S* __restrict__ V,
    const float* __restrict__ anchor, double* __restrict__ Z){
  __shared__ double sY[IT][A_+1];
  __shared__ double sA[A_];
  __shared__ double s_sc[IT][T_];     // scores, then attn (in place)

  int h = blockIdx.x, i0 = blockIdx.y*IT, tid = threadIdx.x;
  int wv = tid>>6, lane = tid&63;
  const S* Qp = Q + h*ST_;
  const S* Kp = K + h*ST_;
  const S* Vp = V + h*ST_;

  for (int f=tid; f<IT*A_; f+=256){
    int i=f/A_, a=f-i*A_;
    sY[i][a] = (double)Qp[(i0+i)*A_ + a];
  }
  if (tid < A_) sA[tid] = (double)anchor[tid];
  __syncthreads();

  // ---- stage B: alpha_qk literal; score = -d^2
  for (int jj=0; jj<2; jj++){
    int j = tid + jj*256;
    const S* Kr = Kp + j*A_;
    double aq[IT];
#pragma unroll
    for (int i=0;i<IT;i++) aq[i]=0.0;
    for (int a=1;a<A_;a++){
      double kv = (double)Kr[a];
#pragma unroll
      for (int i=0;i<IT;i++) aq[i] = fma(sY[i][a], kv, aq[i]);
    }
    double k0 = (double)Kr[0];
#pragma unroll
    for (int i=0;i<IT;i++){
      double alpha = sY[i][0]*k0 - aq[i];
      double d = acosh(fmax(alpha, 1.0+EPS_));
      s_sc[i][j] = -d*d;
    }
  }
  __syncthreads();

  // ---- stage C: softmax per row (wave wv owns rows 2wv, 2wv+1)
  for (int ii=0; ii<2; ii++){
    int i = wv*2 + ii;
    double m = -1.0e300;
#pragma unroll
    for (int kk=0;kk<8;kk++) m = fmax(m, s_sc[i][lane+64*kk]);
    m = wmaxd(m);
    double e[8], sum=0.0;
#pragma unroll
    for (int kk=0;kk<8;kk++){ e[kk]=exp(s_sc[i][lane+64*kk]-m); sum+=e[kk]; }
    sum = wsumd(sum);
#pragma unroll
    for (int kk=0;kk<8;kk++) s_sc[i][lane+64*kk] = e[kk]/sum;
  }
  __syncthreads();

  // ---- stage D: literal per-pair log_map, aggregate, exp_map, project, anchor log_map
  for (int ii=0; ii<2; ii++){
    int i = wv*2 + ii;
    double Ya  = sY[i][lane];
    double Y64 = sY[i][64];
    double acc_a = 0.0, acc64 = 0.0;
    for (int j=0; j<T_; j++){
      double Va  = (double)Vp[j*A_ + lane];
      double V64 = (double)Vp[j*A_ + 64];
      double c = (lane==0) ? fma(Ya, Va, -Y64*V64) : (-Ya*Va);
      double alpha = wsumd(c);                       // -mink(Y,V)
      double dist = acosh(fmax(alpha, 1.0+EPS_));
      double ua  = fma(alpha, Ya,  Va);              // u = V + alpha*Y
      double u64 = fma(alpha, Y64, V64);
      double cm = (lane==0) ? fma(u64,u64, -ua*ua) : ua*ua;
      double muu = wsumd(cm);                        // mink(u,u)
      double un = sqrt(fmax(muu, TINY_));
      double w = s_sc[i][j] * dist / fmax(un, TINY_);
      acc_a = fma(w, ua,  acc_a);
      acc64 = fma(w, u64, acc64);
    }
    // exp_map(Y_row, acc)
    double c2 = (lane==0) ? fma(acc64,acc64, -acc_a*acc_a) : acc_a*acc_a;
    double mv = wsumd(c2);
    double vn = sqrt(fmax(mv, TINY_));
    double ch = cosh(vn);
    double sh = sinh(vn)/fmax(vn, TINY_);
    double ya  = fma(ch, Ya,  sh*acc_a);
    double y64 = fma(ch, Y64, sh*acc64);
    // project
    double c3 = (lane==0) ? fma(y64,y64, -ya*ya) : ya*ya;
    double px = wsumd(c3);
    double scale = sqrt(fmax(fabs(px), TINY_));
    double Pa  = ya/scale; if (lane==0) Pa = fabs(Pa);
    double P64 = y64/scale;
    // log_map(anchor, P)
    double sAl = sA[lane];
    double azc = (lane==0) ? fma(sAl, Pa, -sA[64]*P64) : (-sAl*Pa);
    double az = wsumd(azc);
    double dz = acosh(fmax(az, 1.0+EPS_));
    double uza  = fma(az, sAl,    Pa);
    double uz64 = fma(az, sA[64], P64);
    double c4 = (lane==0) ? fma(uz64,uz64, -uza*uza) : uza*uza;
    double mz = wsumd(c4);
    double unz = sqrt(fmax(mz, TINY_));
    double fz = dz/fmax(unz, TINY_);
    double* Zr = Z + (i0+i)*HA_ + h*A_;
    Zr[lane] = fz*uza;
    if (lane==0) Zr[64] = fz*uz64;
  }
}

// ---------------- kernel 4: out = Z @ Wo + bo (double accumulate)
__global__ __launch_bounds__(256) void k_outD(
    const double* __restrict__ Zb, const float* __restrict__ Wo,
    const float* __restrict__ bo, float* __restrict__ out){
  int c  = blockIdx.x*256 + threadIdx.x;
  int t0 = blockIdx.y*CTT;
  double acc[CTT];
#pragma unroll
  for (int i=0;i<CTT;i++) acc[i]=0.0;
  for (int k=0;k<HA_;k++){
    double w = (double)Wo[k*D_ + c];
#pragma unroll
    for (int i=0;i<CTT;i++) acc[i] = fma(Zb[(t0+i)*HA_ + k], w, acc[i]);
  }
  double bb = (double)bo[c];
#pragma unroll
  for (int i=0;i<CTT;i++) out[(t0+i)*D_ + c] = (float)(acc[i] + bb);
}

template<typename S>
static void run_pipeline(const float* x, const float* Wq, const float* bq,
                         const float* Wk, const float* bk,
                         const float* Wv, const float* bv,
                         const float* Wo, const float* bo, const float* anchor,
                         float* out, char* ws, hipStream_t stream){
  double* Z = (double*)ws;                       // T_*HA_ doubles = 2129920 B
  S* ub = (S*)ws;                                // aliased; dead before Z written
  S* Q  = (S*)(ws + (size_t)T_*HA_*sizeof(double));
  S* K  = Q + H_*ST_;
  S* V  = K + H_*ST_;

  k_projD<S><<<dim3(2, T_/PTT), 256, 0, stream>>>(x, Wq, bq, ub);
  k_liftD<S><<<dim3(T_*H_),      64, 0, stream>>>(ub, Q, 1);
  k_projD<S><<<dim3(2, T_/PTT), 256, 0, stream>>>(x, Wk, bk, ub);
  k_liftD<S><<<dim3(T_*H_),      64, 0, stream>>>(ub, K, 1);
  k_projD<S><<<dim3(2, T_/PTT), 256, 0, stream>>>(x, Wv, bv, ub);
  k_liftD<S><<<dim3(T_*H_),      64, 0, stream>>>(ub, V, 0);
  k_attnD<S><<<dim3(H_, T_/IT), 256, 0, stream>>>(Q, K, V, anchor, Z);
  k_outD   <<<dim3(2, T_/CTT), 256, 0, stream>>>(Z, Wo, bo, out);
}

extern "C" void kernel_launch(void* const* d_in, const int* in_sizes, int n_in,
                              void* d_out, int out_size, void* d_ws, size_t ws_size,
                              hipStream_t stream){
  float* out = (float*)d_out;

  bool ok = (n_in == 10) && (out_size == T_*D_)
    && in_sizes[0]==T_*D_ && in_sizes[1]==D_*HN_ && in_sizes[2]==HN_
    && in_sizes[3]==D_*HN_ && in_sizes[4]==HN_
    && in_sizes[5]==D_*HN_ && in_sizes[6]==HN_
    && in_sizes[7]==HA_*D_ && in_sizes[8]==D_ && in_sizes[9]==A_;
  if (!ok){ k_fill<<<1024,256,0,stream>>>(out, 1.0e12f); return; }

  const float* x      = (const float*)d_in[0];
  const float* Wq     = (const float*)d_in[1];
  const float* bq     = (const float*)d_in[2];
  const float* Wk     = (const float*)d_in[3];
  const float* bk     = (const float*)d_in[4];
  const float* Wv     = (const float*)d_in[5];
  const float* bv     = (const float*)d_in[6];
  const float* Wo     = (const float*)d_in[7];
  const float* bo     = (const float*)d_in[8];
  const float* anchor = (const float*)d_in[9];
  char* ws = (char*)d_ws;

  size_t zbytes = (size_t)T_*HA_*sizeof(double);           // 2129920
  size_t need_d = zbytes + 3ull*H_*ST_*sizeof(double);     // 8519680
  size_t need_f = zbytes + 3ull*H_*ST_*sizeof(float);      // 5324800

  if (ws_size >= need_d){
    run_pipeline<double>(x,Wq,bq,Wk,bk,Wv,bv,Wo,bo,anchor,out,ws,stream);
  } else if (ws_size >= need_f){
    run_pipeline<float>(x,Wq,bq,Wk,bk,Wv,bv,Wo,bo,anchor,out,ws,stream);
  } else {
    k_fill<<<1024,256,0,stream>>>(out, 2.0e12f);
  }
}

// Round 5
// 336.382 us; speedup vs baseline: 4.5574x; 4.5574x over previous
//
#include <hip/hip_runtime.h>
#include <math.h>

#define T_ 512
#define D_ 512
#define H_ 8
#define N_ 64
#define A_ 65
#define HN_ 512
#define HA_ 520
#define ST_ (T_*A_)       // fallback per-head stride
#define QS_ 66            // fast-path Q row stride (f64)
#define VS_ 68            // fast-path V row stride (f32, 16B aligned)
#define KTS_ 512          // fast-path K^T row stride
#define EPS_ 1e-6
#define TINY_ 1e-15
#define IT 8
#define PTT 8
#define CTT 8

__device__ __forceinline__ double wsumd(double v){
#pragma unroll
  for (int o=32;o;o>>=1) v += __shfl_xor(v,o);
  return v;
}
__device__ __forceinline__ double wmaxd(double v){
#pragma unroll
  for (int o=32;o;o>>=1) v = fmax(v,__shfl_xor(v,o));
  return v;
}

__global__ void k_fill(float* __restrict__ out, float val){
  int i = blockIdx.x*256 + threadIdx.x;
  if (i < T_*D_) out[i] = val;
}

// ---------------- proj: u = x @ W + b (f64 accumulate, S-typed output)
template<typename S>
__global__ __launch_bounds__(256) void k_projD(
    const float* __restrict__ x, const float* __restrict__ W,
    const float* __restrict__ b, S* __restrict__ u){
  int c  = blockIdx.x*256 + threadIdx.x;
  int t0 = blockIdx.y*PTT;
  double acc[PTT];
#pragma unroll
  for (int i=0;i<PTT;i++) acc[i]=0.0;
  for (int d=0; d<D_; d++){
    double w = (double)W[d*HN_ + c];
#pragma unroll
    for (int i=0;i<PTT;i++) acc[i] = fma((double)x[(t0+i)*D_ + d], w, acc[i]);
  }
  double bias = (double)b[c];
#pragma unroll
  for (int i=0;i<PTT;i++) u[(t0+i)*HN_ + c] = (S)(acc[i] + bias);
}

// ---------------- FAST lift: f64 rope+lift from f32 proj; 3 output layouts
// mode 0: Q row-major f64[QS_]; mode 1: K^T f64 [66][512]; mode 2: V row f32[VS_] (no rope)
__global__ __launch_bounds__(64) void k_liftF(
    const float* __restrict__ u, double* __restrict__ oQ,
    double* __restrict__ oKT, float* __restrict__ oV, int mode){
  int bid = blockIdx.x;
  int h = bid & 7, t = bid >> 3, n = threadIdx.x;
  double v = (double)u[t*HN_ + h*N_ + n];
  if (mode < 2){
    int fi = n & 31;
    double inv_f = 1.0 / pow(10000.0, (double)(2*fi)*(1.0/64.0));
    double ang = (double)t * inv_f;
    double cs = cos(ang), sn = sin(ang);
    double vp = __shfl_xor(v, 32);
    double rot = (n<32) ? -vp : vp;
    v = v*cs + rot*sn;
  }
  double ss = wsumd(v*v);
  double vn = sqrt(fmax(ss, TINY_));
  double ch = cosh(vn);
  double s  = sinh(vn)/fmax(vn, TINY_);
  double y  = s*v;
  double xx = wsumd(y*y) - ch*ch;
  double scale = sqrt(fmax(fabs(xx), TINY_));
  double y0 = fabs(ch/scale), ya = y/scale;
  if (mode==0){
    double* o = oQ + (size_t)h*T_*QS_ + (size_t)t*QS_;
    if (n==0) o[0] = y0;
    o[n+1] = ya;
  } else if (mode==1){
    double* o = oKT + (size_t)h*66*KTS_ + t;
    if (n==0) o[0] = y0;
    o[(size_t)(n+1)*KTS_] = ya;
  } else {
    float* o = oV + (size_t)h*T_*VS_ + (size_t)t*VS_;
    if (n==0) o[0] = (float)y0;
    o[n+1] = (float)ya;
    if (n<3) o[A_+n] = 0.f;          // zero pads 65..67
  }
}

// ---------------- FAST attention: decomposed aggregation, f64 compute
__global__ __launch_bounds__(256) void k_attnF(
    const double* __restrict__ Qd, const double* __restrict__ KTd,
    const float* __restrict__ Vf, const float* __restrict__ anchor,
    double* __restrict__ Z){
  __shared__ double sYd[IT][VS_];   // Q rows (pads 0)
  __shared__ double sYm[IT][VS_];   // sign-folded: a==0 ? y : -y (pads 0)
  __shared__ double s_w[IT][T_];    // scores -> attn -> w
  __shared__ double sA[A_];
  __shared__ double s_red[4][IT];

  int h = blockIdx.x, i0 = blockIdx.y*IT, tid = threadIdx.x;
  int wv = tid>>6, lane = tid&63;
  const double* Qp = Qd  + (size_t)h*T_*QS_;
  const double* KT = KTd + (size_t)h*66*KTS_;
  const float*  Vp = Vf  + (size_t)h*T_*VS_;

  for (int f=tid; f<IT*VS_; f+=256){
    int i=f/VS_, a=f-i*VS_;
    double v = (a<A_) ? Qp[(size_t)(i0+i)*QS_ + a] : 0.0;
    sYd[i][a] = v;
    sYm[i][a] = (a==0) ? v : -v;
  }
  if (tid < A_) sA[tid] = (double)anchor[tid];
  __syncthreads();

  int j0 = tid, j1 = tid + 256;
  // ---- stage B: alpha_qk = sum_a sYm[i][a]*K[a][j] via K^T (coalesced)
  {
    double aq0[IT], aq1[IT];
#pragma unroll
    for (int i=0;i<IT;i++){ aq0[i]=0.0; aq1[i]=0.0; }
    for (int a=0;a<A_;a++){
      double k0 = KT[(size_t)a*KTS_ + j0];
      double k1 = KT[(size_t)a*KTS_ + j1];
      double ym;
#pragma unroll
      for (int i=0;i<IT;i++){
        ym = sYm[i][a];
        aq0[i] = fma(ym, k0, aq0[i]);
        aq1[i] = fma(ym, k1, aq1[i]);
      }
    }
#pragma unroll
    for (int i=0;i<IT;i++){
      double d0 = acosh(fmax(aq0[i], 1.0+EPS_));
      double d1 = acosh(fmax(aq1[i], 1.0+EPS_));
      s_w[i][j0] = -d0*d0;
      s_w[i][j1] = -d1*d1;
    }
  }
  __syncthreads();

  // ---- stage C: softmax per row (wave wv owns rows 2wv, 2wv+1)
  for (int ii=0; ii<2; ii++){
    int i = wv*2 + ii;
    double m = -1.0e300;
#pragma unroll
    for (int kk=0;kk<8;kk++) m = fmax(m, s_w[i][lane+64*kk]);
    m = wmaxd(m);
    double e[8], sum=0.0;
#pragma unroll
    for (int kk=0;kk<8;kk++){ e[kk]=exp(s_w[i][lane+64*kk]-m); sum+=e[kk]; }
    sum = wsumd(sum);
#pragma unroll
    for (int kk=0;kk<8;kk++) s_w[i][lane+64*kk] = e[kk]/sum;
  }
  __syncthreads();

  // ---- stage B2: alpha_yv (float4 V rows), w = attn*dist/un0, cY partials
  {
    double av0[IT], av1[IT];
#pragma unroll
    for (int i=0;i<IT;i++){ av0[i]=0.0; av1[i]=0.0; }
    const float4* r0 = reinterpret_cast<const float4*>(Vp + (size_t)j0*VS_);
    const float4* r1 = reinterpret_cast<const float4*>(Vp + (size_t)j1*VS_);
    for (int c4=0; c4<VS_/4; c4++){
      float4 va = r0[c4], vb = r1[c4];
      int ab = c4*4;
#pragma unroll
      for (int i=0;i<IT;i++){
        av0[i] = fma(sYm[i][ab+0], (double)va.x, av0[i]);
        av0[i] = fma(sYm[i][ab+1], (double)va.y, av0[i]);
        av0[i] = fma(sYm[i][ab+2], (double)va.z, av0[i]);
        av0[i] = fma(sYm[i][ab+3], (double)va.w, av0[i]);
        av1[i] = fma(sYm[i][ab+0], (double)vb.x, av1[i]);
        av1[i] = fma(sYm[i][ab+1], (double)vb.y, av1[i]);
        av1[i] = fma(sYm[i][ab+2], (double)vb.z, av1[i]);
        av1[i] = fma(sYm[i][ab+3], (double)vb.w, av1[i]);
      }
    }
    const double inv_un0 = 1.0/sqrt(TINY_);   // mink(u,u)=-1-3a^2<=-4 -> TINY clamp, proven r4
    double cyp[IT];
#pragma unroll
    for (int i=0;i<IT;i++){
      double at0 = s_w[i][j0], at1 = s_w[i][j1];
      double d0 = acosh(fmax(av0[i], 1.0+EPS_));
      double d1 = acosh(fmax(av1[i], 1.0+EPS_));
      double w0 = at0*d0*inv_un0;
      double w1 = at1*d1*inv_un0;
      s_w[i][j0] = w0;
      s_w[i][j1] = w1;
      cyp[i] = fma(w0, av0[i], w1*av1[i]);
    }
#pragma unroll
    for (int i=0;i<IT;i++){
      double r = wsumd(cyp[i]);
      if (lane==0) s_red[wv][i] = r;
    }
  }
  __syncthreads();

  // ---- stage D: cV = w @ V (one j loop, 2 rows per wave), then epilogue
  {
    int ra = wv*2, rb = wv*2+1;
    double cya = s_red[0][ra]+s_red[1][ra]+s_red[2][ra]+s_red[3][ra];
    double cyb = s_red[0][rb]+s_red[1][rb]+s_red[2][rb]+s_red[3][rb];
    double aLa=0.0, aLb=0.0, a64a=0.0, a64b=0.0;
    for (int j=0; j<T_; j++){
      double vL  = (double)Vp[(size_t)j*VS_ + lane];
      double v64 = (double)Vp[(size_t)j*VS_ + 64];
      double wa = s_w[ra][j], wb = s_w[rb][j];
      aLa  = fma(wa, vL,  aLa);
      aLb  = fma(wb, vL,  aLb);
      a64a = fma(wa, v64, a64a);
      a64b = fma(wb, v64, a64b);
    }
#pragma unroll
    for (int ii=0; ii<2; ii++){
      int r = (ii==0) ? ra : rb;
      double cy  = (ii==0) ? cya : cyb;
      double ua  = fma(cy, sYd[r][lane], (ii==0)?aLa:aLb);
      double u64 = fma(cy, sYd[r][64],  (ii==0)?a64a:a64b);
      // exp_map(Y, u): literal mink(u,u)
      double c2 = (lane==0) ? fma(u64,u64, -ua*ua) : ua*ua;
      double mv = wsumd(c2);
      double vn = sqrt(fmax(mv, TINY_));
      double ch = cosh(vn);
      double sh = sinh(vn)/fmax(vn, TINY_);
      double ya  = fma(ch, sYd[r][lane], sh*ua);
      double y64 = fma(ch, sYd[r][64],  sh*u64);
      // project
      double c3 = (lane==0) ? fma(y64,y64, -ya*ya) : ya*ya;
      double px = wsumd(c3);
      double scale = sqrt(fmax(fabs(px), TINY_));
      double Pa  = ya/scale; if (lane==0) Pa = fabs(Pa);
      double P64 = y64/scale;
      // log_map(anchor, P), literal
      double sAl = sA[lane];
      double azc = (lane==0) ? fma(sAl, Pa, -sA[64]*P64) : (-sAl*Pa);
      double az = wsumd(azc);
      double dz = acosh(fmax(az, 1.0+EPS_));
      double uza  = fma(az, sAl,    Pa);
      double uz64 = fma(az, sA[64], P64);
      double c4 = (lane==0) ? fma(uz64,uz64, -uza*uza) : uza*uza;
      double mz = wsumd(c4);
      double unz = sqrt(fmax(mz, TINY_));
      double fz = dz/fmax(unz, TINY_);
      double* Zr = Z + (size_t)(i0+r)*HA_ + h*A_;
      Zr[lane] = fz*uza;
      if (lane==0) Zr[64] = fz*uz64;
    }
  }
}

// ---------------- FALLBACK lift (round-4, f32 storage)
template<typename S>
__global__ __launch_bounds__(64) void k_liftD(
    const S* __restrict__ u, S* __restrict__ P, int do_rope){
  int bid = blockIdx.x;
  int h = bid & 7, t = bid >> 3, n = threadIdx.x;
  double v = (double)u[t*HN_ + h*N_ + n];
  if (do_rope){
    int fi = n & 31;
    double inv_f = 1.0 / pow(10000.0, (double)(2*fi)*(1.0/64.0));
    double ang = (double)t * inv_f;
    double cs = cos(ang), sn = sin(ang);
    double vp = __shfl_xor(v, 32);
    double rot = (n<32) ? -vp : vp;
    v = v*cs + rot*sn;
  }
  double ss = wsumd(v*v);
  double vn = sqrt(fmax(ss, TINY_));
  double ch = cosh(vn);
  double s  = sinh(vn)/fmax(vn, TINY_);
  double y  = s*v;
  double xx = wsumd(y*y) - ch*ch;
  double scale = sqrt(fmax(fabs(xx), TINY_));
  S* o = P + h*ST_ + t*A_;
  if (n==0) o[0] = (S)fabs(ch/scale);
  o[n+1] = (S)(y/scale);
}

// ---------------- FALLBACK attention (round-4 literal)
template<typename S>
__global__ __launch_bounds__(256) void k_attnD(
    const S* __restrict__ Q, const S* __restrict__ K, const S* __restrict__ V,
    const float* __restrict__ anchor, double* __restrict__ Z){
  __shared__ double sY[IT][A_+1];
  __shared__ double sA[A_];
  __shared__ double s_sc[IT][T_];

  int h = blockIdx.x, i0 = blockIdx.y*IT, tid = threadIdx.x;
  int wv = tid>>6, lane = tid&63;
  const S* Qp = Q + h*ST_;
  const S* Kp = K + h*ST_;
  const S* Vp = V + h*ST_;

  for (int f=tid; f<IT*A_; f+=256){
    int i=f/A_, a=f-i*A_;
    sY[i][a] = (double)Qp[(i0+i)*A_ + a];
  }
  if (tid < A_) sA[tid] = (double)anchor[tid];
  __syncthreads();

  for (int jj=0; jj<2; jj++){
    int j = tid + jj*256;
    const S* Kr = Kp + j*A_;
    double aq[IT];
#pragma unroll
    for (int i=0;i<IT;i++) aq[i]=0.0;
    for (int a=1;a<A_;a++){
      double kv = (double)Kr[a];
#pragma unroll
      for (int i=0;i<IT;i++) aq[i] = fma(sY[i][a], kv, aq[i]);
    }
    double k0 = (double)Kr[0];
#pragma unroll
    for (int i=0;i<IT;i++){
      double alpha = sY[i][0]*k0 - aq[i];
      double d = acosh(fmax(alpha, 1.0+EPS_));
      s_sc[i][j] = -d*d;
    }
  }
  __syncthreads();

  for (int ii=0; ii<2; ii++){
    int i = wv*2 + ii;
    double m = -1.0e300;
#pragma unroll
    for (int kk=0;kk<8;kk++) m = fmax(m, s_sc[i][lane+64*kk]);
    m = wmaxd(m);
    double e[8], sum=0.0;
#pragma unroll
    for (int kk=0;kk<8;kk++){ e[kk]=exp(s_sc[i][lane+64*kk]-m); sum+=e[kk]; }
    sum = wsumd(sum);
#pragma unroll
    for (int kk=0;kk<8;kk++) s_sc[i][lane+64*kk] = e[kk]/sum;
  }
  __syncthreads();

  for (int ii=0; ii<2; ii++){
    int i = wv*2 + ii;
    double Ya  = sY[i][lane];
    double Y64 = sY[i][64];
    double acc_a = 0.0, acc64 = 0.0;
    for (int j=0; j<T_; j++){
      double Va  = (double)Vp[j*A_ + lane];
      double V64 = (double)Vp[j*A_ + 64];
      double c = (lane==0) ? fma(Ya, Va, -Y64*V64) : (-Ya*Va);
      double alpha = wsumd(c);
      double dist = acosh(fmax(alpha, 1.0+EPS_));
      double ua  = fma(alpha, Ya,  Va);
      double u64 = fma(alpha, Y64, V64);
      double cm = (lane==0) ? fma(u64,u64, -ua*ua) : ua*ua;
      double muu = wsumd(cm);
      double un = sqrt(fmax(muu, TINY_));
      double w = s_sc[i][j] * dist / fmax(un, TINY_);
      acc_a = fma(w, ua,  acc_a);
      acc64 = fma(w, u64, acc64);
    }
    double c2 = (lane==0) ? fma(acc64,acc64, -acc_a*acc_a) : acc_a*acc_a;
    double mv = wsumd(c2);
    double vn = sqrt(fmax(mv, TINY_));
    double ch = cosh(vn);
    double sh = sinh(vn)/fmax(vn, TINY_);
    double ya  = fma(ch, Ya,  sh*acc_a);
    double y64 = fma(ch, Y64, sh*acc64);
    double c3 = (lane==0) ? fma(y64,y64, -ya*ya) : ya*ya;
    double px = wsumd(c3);
    double scale = sqrt(fmax(fabs(px), TINY_));
    double Pa  = ya/scale; if (lane==0) Pa = fabs(Pa);
    double P64 = y64/scale;
    double sAl = sA[lane];
    double azc = (lane==0) ? fma(sAl, Pa, -sA[64]*P64) : (-sAl*Pa);
    double az = wsumd(azc);
    double dz = acosh(fmax(az, 1.0+EPS_));
    double uza  = fma(az, sAl,    Pa);
    double uz64 = fma(az, sA[64], P64);
    double c4 = (lane==0) ? fma(uz64,uz64, -uza*uza) : uza*uza;
    double mz = wsumd(c4);
    double unz = sqrt(fmax(mz, TINY_));
    double fz = dz/fmax(unz, TINY_);
    double* Zr = Z + (i0+i)*HA_ + h*A_;
    Zr[lane] = fz*uza;
    if (lane==0) Zr[64] = fz*uz64;
  }
}

// ---------------- out = Z @ Wo + bo (f64 accumulate)
__global__ __launch_bounds__(256) void k_outD(
    const double* __restrict__ Zb, const float* __restrict__ Wo,
    const float* __restrict__ bo, float* __restrict__ out){
  int c  = blockIdx.x*256 + threadIdx.x;
  int t0 = blockIdx.y*CTT;
  double acc[CTT];
#pragma unroll
  for (int i=0;i<CTT;i++) acc[i]=0.0;
  for (int k=0;k<HA_;k++){
    double w = (double)Wo[k*D_ + c];
#pragma unroll
    for (int i=0;i<CTT;i++) acc[i] = fma(Zb[(t0+i)*HA_ + k], w, acc[i]);
  }
  double bb = (double)bo[c];
#pragma unroll
  for (int i=0;i<CTT;i++) out[(t0+i)*D_ + c] = (float)(acc[i] + bb);
}

extern "C" void kernel_launch(void* const* d_in, const int* in_sizes, int n_in,
                              void* d_out, int out_size, void* d_ws, size_t ws_size,
                              hipStream_t stream){
  float* out = (float*)d_out;

  bool ok = (n_in == 10) && (out_size == T_*D_)
    && in_sizes[0]==T_*D_ && in_sizes[1]==D_*HN_ && in_sizes[2]==HN_
    && in_sizes[3]==D_*HN_ && in_sizes[4]==HN_
    && in_sizes[5]==D_*HN_ && in_sizes[6]==HN_
    && in_sizes[7]==HA_*D_ && in_sizes[8]==D_ && in_sizes[9]==A_;
  if (!ok){ k_fill<<<1024,256,0,stream>>>(out, 1.0e12f); return; }

  const float* x      = (const float*)d_in[0];
  const float* Wq     = (const float*)d_in[1];
  const float* bq     = (const float*)d_in[2];
  const float* Wk     = (const float*)d_in[3];
  const float* bk     = (const float*)d_in[4];
  const float* Wv     = (const float*)d_in[5];
  const float* bv     = (const float*)d_in[6];
  const float* Wo     = (const float*)d_in[7];
  const float* bo     = (const float*)d_in[8];
  const float* anchor = (const float*)d_in[9];
  char* ws = (char*)d_ws;

  size_t zbytes   = (size_t)T_*HA_*sizeof(double);                 // 2,129,920
  size_t qbytes   = (size_t)H_*T_*QS_*sizeof(double);              // 2,162,688
  size_t ktbytes  = (size_t)H_*66*KTS_*sizeof(double);             // 2,162,688
  size_t vbytes   = (size_t)H_*T_*VS_*sizeof(float);               // 1,114,112
  size_t need_fast = zbytes + qbytes + ktbytes + vbytes;           // 7,569,408
  size_t need_f    = zbytes + 3ull*H_*ST_*sizeof(float);           // 5,324,800

  if (ws_size >= need_fast){
    double* Z  = (double*)ws;
    float*  ub = (float*)ws;                       // alias; dead before Z written
    double* Qd = (double*)(ws + zbytes);
    double* KT = (double*)(ws + zbytes + qbytes);
    float*  Vf = (float*) (ws + zbytes + qbytes + ktbytes);

    k_projD<float><<<dim3(2, T_/PTT), 256, 0, stream>>>(x, Wq, bq, ub);
    k_liftF<<<dim3(T_*H_), 64, 0, stream>>>(ub, Qd, KT, Vf, 0);
    k_projD<float><<<dim3(2, T_/PTT), 256, 0, stream>>>(x, Wk, bk, ub);
    k_liftF<<<dim3(T_*H_), 64, 0, stream>>>(ub, Qd, KT, Vf, 1);
    k_projD<float><<<dim3(2, T_/PTT), 256, 0, stream>>>(x, Wv, bv, ub);
    k_liftF<<<dim3(T_*H_), 64, 0, stream>>>(ub, Qd, KT, Vf, 2);
    k_attnF<<<dim3(H_, T_/IT), 256, 0, stream>>>(Qd, KT, Vf, anchor, Z);
    k_outD <<<dim3(2, T_/CTT), 256, 0, stream>>>(Z, Wo, bo, out);
  } else if (ws_size >= need_f){
    double* Z = (double*)ws;
    float* ub = (float*)ws;
    float* Q  = (float*)(ws + zbytes);
    float* K  = Q + H_*ST_;
    float* V  = K + H_*ST_;
    k_projD<float><<<dim3(2, T_/PTT), 256, 0, stream>>>(x, Wq, bq, ub);
    k_liftD<float><<<dim3(T_*H_), 64, 0, stream>>>(ub, Q, 1);
    k_projD<float><<<dim3(2, T_/PTT), 256, 0, stream>>>(x, Wk, bk, ub);
    k_liftD<float><<<dim3(T_*H_), 64, 0, stream>>>(ub, K, 1);
    k_projD<float><<<dim3(2, T_/PTT), 256, 0, stream>>>(x, Wv, bv, ub);
    k_liftD<float><<<dim3(T_*H_), 64, 0, stream>>>(ub, V, 0);
    k_attnD<float><<<dim3(H_, T_/IT), 256, 0, stream>>>(Q, K, V, anchor, Z);
    k_outD<<<dim3(2, T_/CTT), 256, 0, stream>>>(Z, Wo, bo, out);
  } else {
    k_fill<<<1024,256,0,stream>>>(out, 2.0e12f);
  }
}

// Round 6
// 181.794 us; speedup vs baseline: 8.4328x; 1.8504x over previous
//
#include <hip/hip_runtime.h>
#include <math.h>

#define T_ 512
#define D_ 512
#define H_ 8
#define N_ 64
#define A_ 65
#define HN_ 512
#define HA_ 520
#define QS_ 66            // Q row stride (f64)
#define VS_ 68            // V row stride (f32, 16B aligned)
#define KTS_ 512          // K^T row stride (f64)
#define EPS_ 1e-6
#define TINY_ 1e-15
#define IT 4              // query rows per attention block
#define PTT 4             // rows per proj thread
#define CTT 4             // rows per out thread

__device__ __forceinline__ double wsumd(double v){
#pragma unroll
  for (int o=32;o;o>>=1) v += __shfl_xor(v,o);
  return v;
}
__device__ __forceinline__ float wsumf(float v){
#pragma unroll
  for (int o=32;o;o>>=1) v += __shfl_xor(v,o);
  return v;
}
__device__ __forceinline__ float wmaxf(float v){
#pragma unroll
  for (int o=32;o;o>>=1) v = fmaxf(v,__shfl_xor(v,o));
  return v;
}

__global__ void k_fill(float* __restrict__ out, float val){
  int i = blockIdx.x*256 + threadIdx.x;
  if (i < T_*D_) out[i] = val;
}

// ---------------- kernel 1: fused proj (f64 acc) + rope + lift, direct to Q/K^T/V
// grid (2, 3, T_/PTT); wave = one head's 64 dims for PTT rows -> in-register lift
__global__ __launch_bounds__(256) void k_projlift(
    const float* __restrict__ x,
    const float* __restrict__ Wq, const float* __restrict__ bq,
    const float* __restrict__ Wk, const float* __restrict__ bk,
    const float* __restrict__ Wv, const float* __restrict__ bv,
    double* __restrict__ Qd, double* __restrict__ KTd, float* __restrict__ Vf){
  int mode = blockIdx.y;                       // 0=Q(rope),1=K(rope),2=V
  const float* W  = (mode==0)?Wq:((mode==1)?Wk:Wv);
  const float* bb = (mode==0)?bq:((mode==1)?bk:bv);
  int tid = threadIdx.x;
  int c  = blockIdx.x*256 + tid;               // output column 0..511
  int t0 = blockIdx.z*PTT;
  double acc[PTT];
#pragma unroll
  for (int i=0;i<PTT;i++) acc[i]=0.0;
  for (int d=0; d<D_; d+=4){
    double w0 = (double)W[(size_t)(d+0)*HN_ + c];
    double w1 = (double)W[(size_t)(d+1)*HN_ + c];
    double w2 = (double)W[(size_t)(d+2)*HN_ + c];
    double w3 = (double)W[(size_t)(d+3)*HN_ + c];
#pragma unroll
    for (int i=0;i<PTT;i++){
      acc[i] = fma((double)x[(t0+i)*D_ + d+0], w0, acc[i]);
      acc[i] = fma((double)x[(t0+i)*D_ + d+1], w1, acc[i]);
      acc[i] = fma((double)x[(t0+i)*D_ + d+2], w2, acc[i]);
      acc[i] = fma((double)x[(t0+i)*D_ + d+3], w3, acc[i]);
    }
  }
  double bias = (double)bb[c];
  int n = c & 63, h = c >> 6;
  double inv_f = 0.0;
  if (mode < 2) inv_f = 1.0 / pow(10000.0, (double)(2*(n&31))*(1.0/64.0));
#pragma unroll 1
  for (int i=0;i<PTT;i++){
    int t = t0 + i;
    double v = acc[i] + bias;
    if (mode < 2){
      double ang = (double)t * inv_f;
      double vp = __shfl_xor(v, 32);
      double rot = (n<32) ? -vp : vp;
      v = v*cos(ang) + rot*sin(ang);
    }
    // exp_map(origin, [0,v])
    double ss = wsumd(v*v);
    double vn = sqrt(fmax(ss, TINY_));
    double ch = cosh(vn);
    double s  = sinh(vn)/fmax(vn, TINY_);
    double y  = s*v;
    // project
    double xx = wsumd(y*y) - ch*ch;
    double scale = sqrt(fmax(fabs(xx), TINY_));
    double y0 = fabs(ch/scale), ya = y/scale;
    if (mode==0){
      double* o = Qd + (size_t)h*T_*QS_ + (size_t)t*QS_;
      if (n==0) o[0] = y0;
      o[n+1] = ya;
    } else if (mode==1){
      double* o = KTd + (size_t)h*66*KTS_ + t;
      if (n==0) o[0] = y0;
      o[(size_t)(n+1)*KTS_] = ya;
    } else {
      float* o = Vf + (size_t)h*T_*VS_ + (size_t)t*VS_;
      if (n==0) o[0] = (float)y0;
      o[n+1] = (float)ya;
      if (n<3) o[A_+n] = 0.f;                  // zero pads 65..67
    }
  }
}

// ---------------- kernel 2: attention, decomposed aggregation, f64 compute, f32 score LDS
__global__ __launch_bounds__(256) void k_attnF(
    const double* __restrict__ Qd, const double* __restrict__ KTd,
    const float* __restrict__ Vf, const float* __restrict__ anchor,
    double* __restrict__ Z){
  __shared__ double sYd[IT][VS_];   // Q rows (pads 0)
  __shared__ double sYm[IT][VS_];   // sign-folded
  __shared__ float  s_w[IT][T_];    // scores -> attn -> w
  __shared__ double sA[A_];
  __shared__ double s_red[4][IT];

  int h = blockIdx.x, i0 = blockIdx.y*IT, tid = threadIdx.x;
  int wv = tid>>6, lane = tid&63;
  const double* Qp = Qd  + (size_t)h*T_*QS_;
  const double* KT = KTd + (size_t)h*66*KTS_;
  const float*  Vp = Vf  + (size_t)h*T_*VS_;

  for (int f=tid; f<IT*VS_; f+=256){
    int i=f/VS_, a=f-i*VS_;
    double v = (a<A_) ? Qp[(size_t)(i0+i)*QS_ + a] : 0.0;
    sYd[i][a] = v;
    sYm[i][a] = (a==0) ? v : -v;
  }
  if (tid < A_) sA[tid] = (double)anchor[tid];
  __syncthreads();

  int j0 = tid, j1 = tid + 256;
  // ---- stage B: alpha_qk via K^T (coalesced f64), score = -d^2 (store f32)
  {
    double aq0[IT], aq1[IT];
#pragma unroll
    for (int i=0;i<IT;i++){ aq0[i]=0.0; aq1[i]=0.0; }
    for (int a=0;a<A_;a++){
      double k0 = KT[(size_t)a*KTS_ + j0];
      double k1 = KT[(size_t)a*KTS_ + j1];
#pragma unroll
      for (int i=0;i<IT;i++){
        double ym = sYm[i][a];
        aq0[i] = fma(ym, k0, aq0[i]);
        aq1[i] = fma(ym, k1, aq1[i]);
      }
    }
#pragma unroll
    for (int i=0;i<IT;i++){
      double d0 = acosh(fmax(aq0[i], 1.0+EPS_));
      double d1 = acosh(fmax(aq1[i], 1.0+EPS_));
      s_w[i][j0] = (float)(-d0*d0);
      s_w[i][j1] = (float)(-d1*d1);
    }
  }
  __syncthreads();

  // ---- stage C: softmax (f32), wave wv owns row wv
  {
    int i = wv;
    float m = -INFINITY;
#pragma unroll
    for (int kk=0;kk<8;kk++) m = fmaxf(m, s_w[i][lane+64*kk]);
    m = wmaxf(m);
    float e[8], sum=0.f;
#pragma unroll
    for (int kk=0;kk<8;kk++){ e[kk]=expf(s_w[i][lane+64*kk]-m); sum+=e[kk]; }
    sum = wsumf(sum);
#pragma unroll
    for (int kk=0;kk<8;kk++) s_w[i][lane+64*kk] = e[kk]/sum;
  }
  __syncthreads();

  // ---- stage B2: alpha_yv (float4 V), w = attn*dist/un0, cY partials
  {
    double av0[IT], av1[IT];
#pragma unroll
    for (int i=0;i<IT;i++){ av0[i]=0.0; av1[i]=0.0; }
    const float4* r0 = reinterpret_cast<const float4*>(Vp + (size_t)j0*VS_);
    const float4* r1 = reinterpret_cast<const float4*>(Vp + (size_t)j1*VS_);
    for (int c4=0; c4<VS_/4; c4++){
      float4 va = r0[c4], vb = r1[c4];
      int ab = c4*4;
#pragma unroll
      for (int i=0;i<IT;i++){
        av0[i] = fma(sYm[i][ab+0], (double)va.x, av0[i]);
        av0[i] = fma(sYm[i][ab+1], (double)va.y, av0[i]);
        av0[i] = fma(sYm[i][ab+2], (double)va.z, av0[i]);
        av0[i] = fma(sYm[i][ab+3], (double)va.w, av0[i]);
        av1[i] = fma(sYm[i][ab+0], (double)vb.x, av1[i]);
        av1[i] = fma(sYm[i][ab+1], (double)vb.y, av1[i]);
        av1[i] = fma(sYm[i][ab+2], (double)vb.z, av1[i]);
        av1[i] = fma(sYm[i][ab+3], (double)vb.w, av1[i]);
      }
    }
    const double inv_un0 = 1.0/sqrt(TINY_);   // mink(u,u)=-1-3a^2<0 -> TINY clamp (validated r4/r5)
    double cyp[IT];
#pragma unroll
    for (int i=0;i<IT;i++){
      double at0 = (double)s_w[i][j0], at1 = (double)s_w[i][j1];
      double d0 = acosh(fmax(av0[i], 1.0+EPS_));
      double d1 = acosh(fmax(av1[i], 1.0+EPS_));
      double w0 = at0*d0*inv_un0;
      double w1 = at1*d1*inv_un0;
      s_w[i][j0] = (float)w0;
      s_w[i][j1] = (float)w1;
      cyp[i] = fma(w0, av0[i], w1*av1[i]);
    }
#pragma unroll
    for (int i=0;i<IT;i++){
      double r = wsumd(cyp[i]);
      if (lane==0) s_red[wv][i] = r;
    }
  }
  __syncthreads();

  // ---- stage D: cV = w @ V (row r = wv), then literal epilogue
  {
    int r = wv;
    double cy = s_red[0][r]+s_red[1][r]+s_red[2][r]+s_red[3][r];
    double aL = 0.0, a64 = 0.0;
    for (int j=0; j<T_; j++){
      double vL  = (double)Vp[(size_t)j*VS_ + lane];
      double v64 = (double)Vp[(size_t)j*VS_ + 64];
      double w   = (double)s_w[r][j];
      aL  = fma(w, vL,  aL);
      a64 = fma(w, v64, a64);
    }
    double ua  = fma(cy, sYd[r][lane], aL);
    double u64 = fma(cy, sYd[r][64],  a64);
    // exp_map(Y, u): literal mink(u,u)
    double c2 = (lane==0) ? fma(u64,u64, -ua*ua) : ua*ua;
    double mv = wsumd(c2);
    double vn = sqrt(fmax(mv, TINY_));
    double ch = cosh(vn);
    double sh = sinh(vn)/fmax(vn, TINY_);
    double ya  = fma(ch, sYd[r][lane], sh*ua);
    double y64 = fma(ch, sYd[r][64],  sh*u64);
    // project
    double c3 = (lane==0) ? fma(y64,y64, -ya*ya) : ya*ya;
    double px = wsumd(c3);
    double scale = sqrt(fmax(fabs(px), TINY_));
    double Pa  = ya/scale; if (lane==0) Pa = fabs(Pa);
    double P64 = y64/scale;
    // log_map(anchor, P), literal
    double sAl = sA[lane];
    double azc = (lane==0) ? fma(sAl, Pa, -sA[64]*P64) : (-sAl*Pa);
    double az = wsumd(azc);
    double dz = acosh(fmax(az, 1.0+EPS_));
    double uza  = fma(az, sAl,    Pa);
    double uz64 = fma(az, sA[64], P64);
    double c4v = (lane==0) ? fma(uz64,uz64, -uza*uza) : uza*uza;
    double mz = wsumd(c4v);
    double unz = sqrt(fmax(mz, TINY_));
    double fz = dz/fmax(unz, TINY_);
    double* Zr = Z + (size_t)(i0+r)*HA_ + h*A_;
    Zr[lane] = fz*uza;
    if (lane==0) Zr[64] = fz*uz64;
  }
}

// ---------------- kernel 3: out = Z @ Wo + bo (f64 accumulate)
__global__ __launch_bounds__(256) void k_outD(
    const double* __restrict__ Zb, const float* __restrict__ Wo,
    const float* __restrict__ bo, float* __restrict__ out){
  int c  = blockIdx.x*256 + threadIdx.x;
  int t0 = blockIdx.y*CTT;
  double acc[CTT];
#pragma unroll
  for (int i=0;i<CTT;i++) acc[i]=0.0;
  for (int k=0;k<HA_;k+=4){
    double w0 = (double)Wo[(size_t)(k+0)*D_ + c];
    double w1 = (double)Wo[(size_t)(k+1)*D_ + c];
    double w2 = (double)Wo[(size_t)(k+2)*D_ + c];
    double w3 = (double)Wo[(size_t)(k+3)*D_ + c];
#pragma unroll
    for (int i=0;i<CTT;i++){
      const double* zr = Zb + (size_t)(t0+i)*HA_;
      acc[i] = fma(zr[k+0], w0, acc[i]);
      acc[i] = fma(zr[k+1], w1, acc[i]);
      acc[i] = fma(zr[k+2], w2, acc[i]);
      acc[i] = fma(zr[k+3], w3, acc[i]);
    }
  }
  double bb = (double)bo[c];
#pragma unroll
  for (int i=0;i<CTT;i++) out[(t0+i)*D_ + c] = (float)(acc[i] + bb);
}

extern "C" void kernel_launch(void* const* d_in, const int* in_sizes, int n_in,
                              void* d_out, int out_size, void* d_ws, size_t ws_size,
                              hipStream_t stream){
  float* out = (float*)d_out;

  bool ok = (n_in == 10) && (out_size == T_*D_)
    && in_sizes[0]==T_*D_ && in_sizes[1]==D_*HN_ && in_sizes[2]==HN_
    && in_sizes[3]==D_*HN_ && in_sizes[4]==HN_
    && in_sizes[5]==D_*HN_ && in_sizes[6]==HN_
    && in_sizes[7]==HA_*D_ && in_sizes[8]==D_ && in_sizes[9]==A_;
  if (!ok){ k_fill<<<1024,256,0,stream>>>(out, 1.0e12f); return; }

  const float* x      = (const float*)d_in[0];
  const float* Wq     = (const float*)d_in[1];
  const float* bq     = (const float*)d_in[2];
  const float* Wk     = (const float*)d_in[3];
  const float* bk     = (const float*)d_in[4];
  const float* Wv     = (const float*)d_in[5];
  const float* bv     = (const float*)d_in[6];
  const float* Wo     = (const float*)d_in[7];
  const float* bo     = (const float*)d_in[8];
  const float* anchor = (const float*)d_in[9];
  char* ws = (char*)d_ws;

  size_t zbytes  = (size_t)T_*HA_*sizeof(double);           // 2,129,920
  size_t qbytes  = (size_t)H_*T_*QS_*sizeof(double);        // 2,162,688
  size_t ktbytes = (size_t)H_*66*KTS_*sizeof(double);       // 2,162,688
  size_t vbytes  = (size_t)H_*T_*VS_*sizeof(float);         // 1,114,112
  size_t need    = zbytes + qbytes + ktbytes + vbytes;      // 7,569,408 (validated r5)
  if (ws_size < need){ k_fill<<<1024,256,0,stream>>>(out, 2.0e12f); return; }

  double* Z  = (double*)ws;
  double* Qd = (double*)(ws + zbytes);
  double* KT = (double*)(ws + zbytes + qbytes);
  float*  Vf = (float*) (ws + zbytes + qbytes + ktbytes);

  k_projlift<<<dim3(2,3,T_/PTT), 256, 0, stream>>>(x, Wq,bq, Wk,bk, Wv,bv, Qd, KT, Vf);
  k_attnF   <<<dim3(H_, T_/IT),  256, 0, stream>>>(Qd, KT, Vf, anchor, Z);
  k_outD    <<<dim3(2, T_/CTT),  256, 0, stream>>>(Z, Wo, bo, out);
}

// Round 7
// 157.370 us; speedup vs baseline: 9.7416x; 1.1552x over previous
//
#include <hip/hip_runtime.h>
#include <math.h>

#define T_ 512
#define D_ 512
#define H_ 8
#define N_ 64
#define A_ 65
#define HN_ 512
#define HA_ 520
#define QS_ 66            // Q row stride (f64)
#define VS_ 66            // V row stride (f32)
#define KTS_ 512          // K^T / V^T row stride
#define EPS_ 1e-6
#define TINY_ 1e-15
#define IT 4              // query rows per attention block (= #waves)
#define PTT 4             // rows per proj thread
#define CTT 2             // rows per out thread

__device__ __forceinline__ double wsumd(double v){
#pragma unroll
  for (int o=32;o;o>>=1) v += __shfl_xor(v,o);
  return v;
}
__device__ __forceinline__ float wsumf(float v){
#pragma unroll
  for (int o=32;o;o>>=1) v += __shfl_xor(v,o);
  return v;
}
__device__ __forceinline__ float wmaxf(float v){
#pragma unroll
  for (int o=32;o;o>>=1) v = fmaxf(v,__shfl_xor(v,o));
  return v;
}

__global__ void k_fill(float* __restrict__ out, float val){
  int i = blockIdx.x*256 + threadIdx.x;
  if (i < T_*D_) out[i] = val;
}

// ---------------- kernel 1: fused proj (f64 acc) + rope + lift -> Q / K^T / (V rows + V^T)
// grid (2, 3, T_/PTT); each wave = one head's 64 dims for PTT rows -> in-register lift
__global__ __launch_bounds__(256) void k_projlift(
    const float* __restrict__ x,
    const float* __restrict__ Wq, const float* __restrict__ bq,
    const float* __restrict__ Wk, const float* __restrict__ bk,
    const float* __restrict__ Wv, const float* __restrict__ bv,
    double* __restrict__ Qd, double* __restrict__ KTd,
    float* __restrict__ Vf, float* __restrict__ VTf){
  int mode = blockIdx.y;                       // 0=Q(rope),1=K(rope),2=V
  const float* W  = (mode==0)?Wq:((mode==1)?Wk:Wv);
  const float* bb = (mode==0)?bq:((mode==1)?bk:bv);
  int tid = threadIdx.x;
  int c  = blockIdx.x*256 + tid;               // output column 0..511
  int t0 = blockIdx.z*PTT;
  double acc[PTT];
#pragma unroll
  for (int i=0;i<PTT;i++) acc[i]=0.0;
  for (int d=0; d<D_; d+=4){
    double w0 = (double)W[(size_t)(d+0)*HN_ + c];
    double w1 = (double)W[(size_t)(d+1)*HN_ + c];
    double w2 = (double)W[(size_t)(d+2)*HN_ + c];
    double w3 = (double)W[(size_t)(d+3)*HN_ + c];
#pragma unroll
    for (int i=0;i<PTT;i++){
      acc[i] = fma((double)x[(t0+i)*D_ + d+0], w0, acc[i]);
      acc[i] = fma((double)x[(t0+i)*D_ + d+1], w1, acc[i]);
      acc[i] = fma((double)x[(t0+i)*D_ + d+2], w2, acc[i]);
      acc[i] = fma((double)x[(t0+i)*D_ + d+3], w3, acc[i]);
    }
  }
  double bias = (double)bb[c];
  int n = c & 63, h = c >> 6;
  double inv_f = 0.0;
  if (mode < 2) inv_f = 1.0 / pow(10000.0, (double)(2*(n&31))*(1.0/64.0));
#pragma unroll 1
  for (int i=0;i<PTT;i++){
    int t = t0 + i;
    double v = acc[i] + bias;
    if (mode < 2){
      double ang = (double)t * inv_f;
      double vp = __shfl_xor(v, 32);
      double rot = (n<32) ? -vp : vp;
      v = v*cos(ang) + rot*sin(ang);
    }
    // exp_map(origin, [0,v])
    double ss = wsumd(v*v);
    double vn = sqrt(fmax(ss, TINY_));
    double ch = cosh(vn);
    double s  = sinh(vn)/fmax(vn, TINY_);
    double y  = s*v;
    // project
    double xx = wsumd(y*y) - ch*ch;
    double scale = sqrt(fmax(fabs(xx), TINY_));
    double y0 = fabs(ch/scale), ya = y/scale;
    if (mode==0){
      double* o = Qd + (size_t)h*T_*QS_ + (size_t)t*QS_;
      if (n==0) o[0] = y0;
      o[n+1] = ya;
    } else if (mode==1){
      double* o = KTd + (size_t)h*66*KTS_ + t;
      if (n==0) o[0] = y0;
      o[(size_t)(n+1)*KTS_] = ya;
    } else {
      float y0f = (float)y0, yaf = (float)ya;
      float* o = Vf + (size_t)h*T_*VS_ + (size_t)t*VS_;
      if (n==0) o[0] = y0f;
      o[n+1] = yaf;
      float* ot = VTf + (size_t)h*66*KTS_ + t;
      if (n==0) ot[0] = y0f;
      ot[(size_t)(n+1)*KTS_] = yaf;
    }
  }
}

// ---------------- kernel 2: attention; coalesced B/B2 via transposed layouts, j-split D
__global__ __launch_bounds__(256) void k_attnF(
    const double* __restrict__ Qd, const double* __restrict__ KTd,
    const float* __restrict__ VTf, const float* __restrict__ Vf,
    const float* __restrict__ anchor, float* __restrict__ Z){
  __shared__ double sYd[IT][QS_];     // Q rows
  __shared__ double sYm[IT][QS_];     // sign-folded
  __shared__ float  s_w[IT][T_];      // scores -> attn -> w
  __shared__ double sA[A_];
  __shared__ double s_red[4][IT];     // cY partials
  __shared__ double s_part[4][IT][64];// w@V lane partials
  __shared__ double s_p64[4][IT];     // w@V dim-64 partials

  int h = blockIdx.x, i0 = blockIdx.y*IT, tid = threadIdx.x;
  int wv = tid>>6, lane = tid&63;
  const double* Qp = Qd  + (size_t)h*T_*QS_;
  const double* KT = KTd + (size_t)h*66*KTS_;
  const float*  VT = VTf + (size_t)h*66*KTS_;
  const float*  Vp = Vf  + (size_t)h*T_*VS_;

  for (int f=tid; f<IT*QS_; f+=256){
    int i=f/QS_, a=f-i*QS_;
    double v = (a<A_) ? Qp[(size_t)(i0+i)*QS_ + a] : 0.0;
    sYd[i][a] = v;
    sYm[i][a] = (a==0) ? v : -v;
  }
  if (tid < A_) sA[tid] = (double)anchor[tid];
  __syncthreads();

  int j0 = tid, j1 = tid + 256;
  // ---- stage B: alpha_qk via K^T (coalesced f64), score = -d^2 (store f32)
  {
    double aq0[IT], aq1[IT];
#pragma unroll
    for (int i=0;i<IT;i++){ aq0[i]=0.0; aq1[i]=0.0; }
    for (int a=0;a<A_;a++){
      double k0 = KT[(size_t)a*KTS_ + j0];
      double k1 = KT[(size_t)a*KTS_ + j1];
#pragma unroll
      for (int i=0;i<IT;i++){
        double ym = sYm[i][a];
        aq0[i] = fma(ym, k0, aq0[i]);
        aq1[i] = fma(ym, k1, aq1[i]);
      }
    }
#pragma unroll
    for (int i=0;i<IT;i++){
      double d0 = acosh(fmax(aq0[i], 1.0+EPS_));
      double d1 = acosh(fmax(aq1[i], 1.0+EPS_));
      s_w[i][j0] = (float)(-d0*d0);
      s_w[i][j1] = (float)(-d1*d1);
    }
  }
  __syncthreads();

  // ---- stage C: softmax (f32), wave wv owns row wv
  {
    int i = wv;
    float m = -INFINITY;
#pragma unroll
    for (int kk=0;kk<8;kk++) m = fmaxf(m, s_w[i][lane+64*kk]);
    m = wmaxf(m);
    float e[8], sum=0.f;
#pragma unroll
    for (int kk=0;kk<8;kk++){ e[kk]=expf(s_w[i][lane+64*kk]-m); sum+=e[kk]; }
    sum = wsumf(sum);
#pragma unroll
    for (int kk=0;kk<8;kk++) s_w[i][lane+64*kk] = e[kk]/sum;
  }
  __syncthreads();

  // ---- stage B2: alpha_yv via V^T (coalesced f32), w = attn*dist/un0, cY partials
  {
    double av0[IT], av1[IT];
#pragma unroll
    for (int i=0;i<IT;i++){ av0[i]=0.0; av1[i]=0.0; }
    for (int a=0;a<A_;a++){
      double v0 = (double)VT[(size_t)a*KTS_ + j0];
      double v1 = (double)VT[(size_t)a*KTS_ + j1];
#pragma unroll
      for (int i=0;i<IT;i++){
        double ym = sYm[i][a];
        av0[i] = fma(ym, v0, av0[i]);
        av1[i] = fma(ym, v1, av1[i]);
      }
    }
    const double inv_un0 = 1.0/sqrt(TINY_);   // mink(u,u)=-1-3a^2<0 -> TINY clamp (validated r4-r6)
    double cyp[IT];
#pragma unroll
    for (int i=0;i<IT;i++){
      double at0 = (double)s_w[i][j0], at1 = (double)s_w[i][j1];
      double d0 = acosh(fmax(av0[i], 1.0+EPS_));
      double d1 = acosh(fmax(av1[i], 1.0+EPS_));
      double w0 = at0*d0*inv_un0;
      double w1 = at1*d1*inv_un0;
      s_w[i][j0] = (float)w0;
      s_w[i][j1] = (float)w1;
      cyp[i] = fma(w0, av0[i], w1*av1[i]);
    }
#pragma unroll
    for (int i=0;i<IT;i++){
      double r = wsumd(cyp[i]);
      if (lane==0) s_red[wv][i] = r;
    }
  }
  __syncthreads();

  // ---- stage D: w @ V, j-split (wave wv owns j in [wv*128, wv*128+128) for ALL rows)
  {
    double pL[IT], p64[IT];
#pragma unroll
    for (int i=0;i<IT;i++){ pL[i]=0.0; p64[i]=0.0; }
    int jb = wv*128;
    for (int jj=0; jj<128; jj++){
      int j = jb + jj;
      double vL = (double)Vp[(size_t)j*VS_ + lane];
#pragma unroll
      for (int i=0;i<IT;i++){
        double w = (double)s_w[i][j];
        pL[i] = fma(w, vL, pL[i]);
      }
    }
    // dim-64 via coalesced VT row 64, lane-parallel over j
#pragma unroll
    for (int cc=0; cc<2; cc++){
      int j = jb + cc*64 + lane;
      double v64 = (double)VT[(size_t)64*KTS_ + j];
#pragma unroll
      for (int i=0;i<IT;i++){
        double w = (double)s_w[i][j];
        p64[i] = fma(w, v64, p64[i]);
      }
    }
#pragma unroll
    for (int i=0;i<IT;i++){
      s_part[wv][i][lane] = pL[i];
      double r = wsumd(p64[i]);
      if (lane==0) s_p64[wv][i] = r;
    }
  }
  __syncthreads();

  // ---- epilogue: wave wv handles row r=wv; literal exp_map/project/anchor log_map
  {
    int r = wv;
    double cy = s_red[0][r]+s_red[1][r]+s_red[2][r]+s_red[3][r];
    double aL = s_part[0][r][lane]+s_part[1][r][lane]+s_part[2][r][lane]+s_part[3][r][lane];
    double a64 = s_p64[0][r]+s_p64[1][r]+s_p64[2][r]+s_p64[3][r];
    double ua  = fma(cy, sYd[r][lane], aL);
    double u64 = fma(cy, sYd[r][64],  a64);
    // exp_map(Y, u): literal mink(u,u)
    double c2 = (lane==0) ? fma(u64,u64, -ua*ua) : ua*ua;
    double mv = wsumd(c2);
    double vn = sqrt(fmax(mv, TINY_));
    double ch = cosh(vn);
    double sh = sinh(vn)/fmax(vn, TINY_);
    double ya  = fma(ch, sYd[r][lane], sh*ua);
    double y64 = fma(ch, sYd[r][64],  sh*u64);
    // project
    double c3 = (lane==0) ? fma(y64,y64, -ya*ya) : ya*ya;
    double px = wsumd(c3);
    double scale = sqrt(fmax(fabs(px), TINY_));
    double Pa  = ya/scale; if (lane==0) Pa = fabs(Pa);
    double P64 = y64/scale;
    // log_map(anchor, P), literal
    double sAl = sA[lane];
    double azc = (lane==0) ? fma(sAl, Pa, -sA[64]*P64) : (-sAl*Pa);
    double az = wsumd(azc);
    double dz = acosh(fmax(az, 1.0+EPS_));
    double uza  = fma(az, sAl,    Pa);
    double uz64 = fma(az, sA[64], P64);
    double c4v = (lane==0) ? fma(uz64,uz64, -uza*uza) : uza*uza;
    double mz = wsumd(c4v);
    double unz = sqrt(fmax(mz, TINY_));
    double fz = dz/fmax(unz, TINY_);
    float* Zr = Z + (size_t)(i0+r)*HA_ + h*A_;
    Zr[lane] = (float)(fz*uza);
    if (lane==0) Zr[64] = (float)(fz*uz64);
  }
}

// ---------------- kernel 3: out = Z @ Wo + bo (f64 accumulate, f32 Z)
__global__ __launch_bounds__(256) void k_outD(
    const float* __restrict__ Zb, const float* __restrict__ Wo,
    const float* __restrict__ bo, float* __restrict__ out){
  int c  = blockIdx.x*256 + threadIdx.x;
  int t0 = blockIdx.y*CTT;
  double acc[CTT];
#pragma unroll
  for (int i=0;i<CTT;i++) acc[i]=0.0;
  for (int k=0;k<HA_;k+=4){
    double w0 = (double)Wo[(size_t)(k+0)*D_ + c];
    double w1 = (double)Wo[(size_t)(k+1)*D_ + c];
    double w2 = (double)Wo[(size_t)(k+2)*D_ + c];
    double w3 = (double)Wo[(size_t)(k+3)*D_ + c];
#pragma unroll
    for (int i=0;i<CTT;i++){
      const float* zr = Zb + (size_t)(t0+i)*HA_;
      acc[i] = fma((double)zr[k+0], w0, acc[i]);
      acc[i] = fma((double)zr[k+1], w1, acc[i]);
      acc[i] = fma((double)zr[k+2], w2, acc[i]);
      acc[i] = fma((double)zr[k+3], w3, acc[i]);
    }
  }
  double bb = (double)bo[c];
#pragma unroll
  for (int i=0;i<CTT;i++) out[(t0+i)*D_ + c] = (float)(acc[i] + bb);
}

extern "C" void kernel_launch(void* const* d_in, const int* in_sizes, int n_in,
                              void* d_out, int out_size, void* d_ws, size_t ws_size,
                              hipStream_t stream){
  float* out = (float*)d_out;

  bool ok = (n_in == 10) && (out_size == T_*D_)
    && in_sizes[0]==T_*D_ && in_sizes[1]==D_*HN_ && in_sizes[2]==HN_
    && in_sizes[3]==D_*HN_ && in_sizes[4]==HN_
    && in_sizes[5]==D_*HN_ && in_sizes[6]==HN_
    && in_sizes[7]==HA_*D_ && in_sizes[8]==D_ && in_sizes[9]==A_;
  if (!ok){ k_fill<<<1024,256,0,stream>>>(out, 1.0e12f); return; }

  const float* x      = (const float*)d_in[0];
  const float* Wq     = (const float*)d_in[1];
  const float* bq     = (const float*)d_in[2];
  const float* Wk     = (const float*)d_in[3];
  const float* bk     = (const float*)d_in[4];
  const float* Wv     = (const float*)d_in[5];
  const float* bv     = (const float*)d_in[6];
  const float* Wo     = (const float*)d_in[7];
  const float* bo     = (const float*)d_in[8];
  const float* anchor = (const float*)d_in[9];
  char* ws = (char*)d_ws;

  size_t zbytes  = (size_t)T_*HA_*sizeof(float);            // 1,064,960
  size_t qbytes  = (size_t)H_*T_*QS_*sizeof(double);        // 2,162,688
  size_t ktbytes = (size_t)H_*66*KTS_*sizeof(double);       // 2,162,688
  size_t vbytes  = (size_t)H_*T_*VS_*sizeof(float);         // 1,081,344
  size_t vtbytes = (size_t)H_*66*KTS_*sizeof(float);        // 1,081,344
  size_t need    = zbytes+qbytes+ktbytes+vbytes+vtbytes;    // 7,553,024 <= proven 7,569,408
  if (ws_size < need){ k_fill<<<1024,256,0,stream>>>(out, 2.0e12f); return; }

  float*  Zf = (float*)ws;
  double* Qd = (double*)(ws + zbytes);
  double* KT = (double*)(ws + zbytes + qbytes);
  float*  Vf = (float*) (ws + zbytes + qbytes + ktbytes);
  float*  VT = (float*) (ws + zbytes + qbytes + ktbytes + vbytes);

  k_projlift<<<dim3(2,3,T_/PTT), 256, 0, stream>>>(x, Wq,bq, Wk,bk, Wv,bv, Qd, KT, Vf, VT);
  k_attnF   <<<dim3(H_, T_/IT),  256, 0, stream>>>(Qd, KT, VT, Vf, anchor, Zf);
  k_outD    <<<dim3(2, T_/CTT),  256, 0, stream>>>(Zf, Wo, bo, out);
}

// Round 8
// 102.035 us; speedup vs baseline: 15.0245x; 1.5423x over previous
//
#include <hip/hip_runtime.h>
#include <math.h>

#define T_ 512
#define D_ 512
#define H_ 8
#define N_ 64
#define A_ 65
#define HN_ 512
#define HA_ 520
#define QS_ 66            // Q row stride (f64)
#define VS_ 66            // V row stride (f32)
#define KTS_ 512          // K^T / V^T row stride
#define EPS_ 1e-6
#define EPSF_ 1e-6f
#define TINY_ 1e-15
#define IT 4              // query rows per attention block (= #waves)
#define PTT 4             // rows per proj thread
#define CTT 2             // rows per out thread

__device__ __forceinline__ double wsumd(double v){
#pragma unroll
  for (int o=32;o;o>>=1) v += __shfl_xor(v,o);
  return v;
}
__device__ __forceinline__ float wsumf(float v){
#pragma unroll
  for (int o=32;o;o>>=1) v += __shfl_xor(v,o);
  return v;
}
__device__ __forceinline__ float wmaxf(float v){
#pragma unroll
  for (int o=32;o;o>>=1) v = fmaxf(v,__shfl_xor(v,o));
  return v;
}

__global__ void k_fill(float* __restrict__ out, float val){
  int i = blockIdx.x*256 + threadIdx.x;
  if (i < T_*D_) out[i] = val;
}

// ---------------- kernel 1: f32 proj GEMM + f64 rope/lift -> Qf64 / KT f32 / V,VT f32
// grid (2, 3, T_/PTT); each wave = one head's 64 dims for PTT rows -> in-register lift
__global__ __launch_bounds__(256) void k_projlift(
    const float* __restrict__ x,
    const float* __restrict__ Wq, const float* __restrict__ bq,
    const float* __restrict__ Wk, const float* __restrict__ bk,
    const float* __restrict__ Wv, const float* __restrict__ bv,
    double* __restrict__ Qd, float* __restrict__ KTf,
    float* __restrict__ Vf, float* __restrict__ VTf){
  int mode = blockIdx.y;                       // 0=Q(rope),1=K(rope),2=V
  const float* W  = (mode==0)?Wq:((mode==1)?Wk:Wv);
  const float* bb = (mode==0)?bq:((mode==1)?bk:bv);
  int tid = threadIdx.x;
  int c  = blockIdx.x*256 + tid;               // output column 0..511
  int t0 = blockIdx.z*PTT;
  float acc[PTT];
#pragma unroll
  for (int i=0;i<PTT;i++) acc[i]=0.f;
  for (int d=0; d<D_; d+=4){
    float w0 = W[(size_t)(d+0)*HN_ + c];
    float w1 = W[(size_t)(d+1)*HN_ + c];
    float w2 = W[(size_t)(d+2)*HN_ + c];
    float w3 = W[(size_t)(d+3)*HN_ + c];
#pragma unroll
    for (int i=0;i<PTT;i++){
      acc[i] = fmaf(x[(t0+i)*D_ + d+0], w0, acc[i]);
      acc[i] = fmaf(x[(t0+i)*D_ + d+1], w1, acc[i]);
      acc[i] = fmaf(x[(t0+i)*D_ + d+2], w2, acc[i]);
      acc[i] = fmaf(x[(t0+i)*D_ + d+3], w3, acc[i]);
    }
  }
  float bias = bb[c];
  int n = c & 63, h = c >> 6;
  double inv_f = 0.0;
  if (mode < 2) inv_f = 1.0 / pow(10000.0, (double)(2*(n&31))*(1.0/64.0));
#pragma unroll 1
  for (int i=0;i<PTT;i++){
    int t = t0 + i;
    double v = (double)(acc[i] + bias);         // f32 GEMM result (np-matching)
    if (mode < 2){
      double ang = (double)t * inv_f;
      double vp = __shfl_xor(v, 32);
      double rot = (n<32) ? -vp : vp;
      v = v*cos(ang) + rot*sin(ang);
    }
    // f64 lift: exp_map(origin, [0,v]) + project (cancellation-sensitive, stays f64)
    double ss = wsumd(v*v);
    double vn = sqrt(fmax(ss, TINY_));
    double ch = cosh(vn);
    double s  = sinh(vn)/fmax(vn, TINY_);
    double y  = s*v;
    double xx = wsumd(y*y) - ch*ch;
    double scale = sqrt(fmax(fabs(xx), TINY_));
    double y0 = fabs(ch/scale), ya = y/scale;
    if (mode==0){
      double* o = Qd + (size_t)h*T_*QS_ + (size_t)t*QS_;
      if (n==0) o[0] = y0;
      o[n+1] = ya;
    } else if (mode==1){
      float* o = KTf + (size_t)h*66*KTS_ + t;
      if (n==0) o[0] = (float)y0;
      o[(size_t)(n+1)*KTS_] = (float)ya;
    } else {
      float y0f = (float)y0, yaf = (float)ya;
      float* o = Vf + (size_t)h*T_*VS_ + (size_t)t*VS_;
      if (n==0) o[0] = y0f;
      o[n+1] = yaf;
      float* ot = VTf + (size_t)h*66*KTS_ + t;
      if (n==0) ot[0] = y0f;
      ot[(size_t)(n+1)*KTS_] = yaf;
    }
  }
}

// ---------------- kernel 2: attention; f32 dot stages, f64 epilogue
__global__ __launch_bounds__(256) void k_attnF(
    const double* __restrict__ Qd, const float* __restrict__ KTf,
    const float* __restrict__ VTf, const float* __restrict__ Vf,
    const float* __restrict__ anchor, float* __restrict__ Z){
  __shared__ double sYd[IT][QS_];     // Q rows f64 (epilogue)
  __shared__ float  sYm[IT][QS_];     // sign-folded f32 (dots)
  __shared__ float  s_w[IT][T_];      // scores -> attn -> w
  __shared__ double sA[A_];
  __shared__ float  s_red[4][IT];     // cY partials
  __shared__ float  s_part[4][IT][64];// w@V lane partials
  __shared__ float  s_p64[4][IT];     // w@V dim-64 partials

  int h = blockIdx.x, i0 = blockIdx.y*IT, tid = threadIdx.x;
  int wv = tid>>6, lane = tid&63;
  const double* Qp = Qd  + (size_t)h*T_*QS_;
  const float*  KT = KTf + (size_t)h*66*KTS_;
  const float*  VT = VTf + (size_t)h*66*KTS_;
  const float*  Vp = Vf  + (size_t)h*T_*VS_;

  for (int f=tid; f<IT*QS_; f+=256){
    int i=f/QS_, a=f-i*QS_;
    double v = (a<A_) ? Qp[(size_t)(i0+i)*QS_ + a] : 0.0;
    sYd[i][a] = v;
    sYm[i][a] = (float)((a==0) ? v : -v);
  }
  if (tid < A_) sA[tid] = (double)anchor[tid];
  __syncthreads();

  int j0 = tid, j1 = tid + 256;
  // ---- stage B: alpha_qk via K^T (f32, coalesced); score = -d^2
  // near-clamp alpha->1+ gives d^2->0: softmax-insensitive exactly where acosh ill-conditioned
  {
    float aq0[IT], aq1[IT];
#pragma unroll
    for (int i=0;i<IT;i++){ aq0[i]=0.f; aq1[i]=0.f; }
    for (int a=0;a<A_;a++){
      float k0 = KT[(size_t)a*KTS_ + j0];
      float k1 = KT[(size_t)a*KTS_ + j1];
#pragma unroll
      for (int i=0;i<IT;i++){
        float ym = sYm[i][a];
        aq0[i] = fmaf(ym, k0, aq0[i]);
        aq1[i] = fmaf(ym, k1, aq1[i]);
      }
    }
#pragma unroll
    for (int i=0;i<IT;i++){
      float d0 = acoshf(fmaxf(aq0[i], 1.f+EPSF_));
      float d1 = acoshf(fmaxf(aq1[i], 1.f+EPSF_));
      s_w[i][j0] = -d0*d0;
      s_w[i][j1] = -d1*d1;
    }
  }
  __syncthreads();

  // ---- stage C: softmax (f32), wave wv owns row wv
  {
    int i = wv;
    float m = -INFINITY;
#pragma unroll
    for (int kk=0;kk<8;kk++) m = fmaxf(m, s_w[i][lane+64*kk]);
    m = wmaxf(m);
    float e[8], sum=0.f;
#pragma unroll
    for (int kk=0;kk<8;kk++){ e[kk]=expf(s_w[i][lane+64*kk]-m); sum+=e[kk]; }
    sum = wsumf(sum);
#pragma unroll
    for (int kk=0;kk<8;kk++) s_w[i][lane+64*kk] = e[kk]/sum;
  }
  __syncthreads();

  // ---- stage B2: alpha_yv via V^T (f32); w = attn*dist/un0; cY partials
  // dist->0 where acosh ill-conditioned => w->0 => error absolutely bounded
  {
    float av0[IT], av1[IT];
#pragma unroll
    for (int i=0;i<IT;i++){ av0[i]=0.f; av1[i]=0.f; }
    for (int a=0;a<A_;a++){
      float v0 = VT[(size_t)a*KTS_ + j0];
      float v1 = VT[(size_t)a*KTS_ + j1];
#pragma unroll
      for (int i=0;i<IT;i++){
        float ym = sYm[i][a];
        av0[i] = fmaf(ym, v0, av0[i]);
        av1[i] = fmaf(ym, v1, av1[i]);
      }
    }
    const float inv_un0 = 3.16227766016838e7f;  // 1/sqrt(TINY); mink(u,u)<0 proven r4-r7
    float cyp[IT];
#pragma unroll
    for (int i=0;i<IT;i++){
      float at0 = s_w[i][j0], at1 = s_w[i][j1];
      float d0 = acoshf(fmaxf(av0[i], 1.f+EPSF_));
      float d1 = acoshf(fmaxf(av1[i], 1.f+EPSF_));
      float w0 = at0*d0*inv_un0;
      float w1 = at1*d1*inv_un0;
      s_w[i][j0] = w0;
      s_w[i][j1] = w1;
      cyp[i] = fmaf(w0, av0[i], w1*av1[i]);
    }
#pragma unroll
    for (int i=0;i<IT;i++){
      float r = wsumf(cyp[i]);
      if (lane==0) s_red[wv][i] = r;
    }
  }
  __syncthreads();

  // ---- stage D: w @ V (f32), j-split: wave wv owns j in [wv*128, +128) for ALL rows
  {
    float pL[IT], p64[IT];
#pragma unroll
    for (int i=0;i<IT;i++){ pL[i]=0.f; p64[i]=0.f; }
    int jb = wv*128;
    for (int jj=0; jj<128; jj++){
      int j = jb + jj;
      float vL = Vp[(size_t)j*VS_ + lane];
#pragma unroll
      for (int i=0;i<IT;i++) pL[i] = fmaf(s_w[i][j], vL, pL[i]);
    }
#pragma unroll
    for (int cc=0; cc<2; cc++){
      int j = jb + cc*64 + lane;
      float v64 = VT[(size_t)64*KTS_ + j];
#pragma unroll
      for (int i=0;i<IT;i++) p64[i] = fmaf(s_w[i][j], v64, p64[i]);
    }
#pragma unroll
    for (int i=0;i<IT;i++){
      s_part[wv][i][lane] = pL[i];
      float r = wsumf(p64[i]);
      if (lane==0) s_p64[wv][i] = r;
    }
  }
  __syncthreads();

  // ---- epilogue (f64, unchanged from proven r6/r7): exp_map/project/anchor log_map
  {
    int r = wv;
    double cy = (double)s_red[0][r]+(double)s_red[1][r]+(double)s_red[2][r]+(double)s_red[3][r];
    double aL = (double)s_part[0][r][lane]+(double)s_part[1][r][lane]
              + (double)s_part[2][r][lane]+(double)s_part[3][r][lane];
    double a64 = (double)s_p64[0][r]+(double)s_p64[1][r]+(double)s_p64[2][r]+(double)s_p64[3][r];
    double ua  = fma(cy, sYd[r][lane], aL);
    double u64 = fma(cy, sYd[r][64],  a64);
    double c2 = (lane==0) ? fma(u64,u64, -ua*ua) : ua*ua;
    double mv = wsumd(c2);
    double vn = sqrt(fmax(mv, TINY_));
    double ch = cosh(vn);
    double sh = sinh(vn)/fmax(vn, TINY_);
    double ya  = fma(ch, sYd[r][lane], sh*ua);
    double y64 = fma(ch, sYd[r][64],  sh*u64);
    double c3 = (lane==0) ? fma(y64,y64, -ya*ya) : ya*ya;
    double px = wsumd(c3);
    double scale = sqrt(fmax(fabs(px), TINY_));
    double Pa  = ya/scale; if (lane==0) Pa = fabs(Pa);
    double P64 = y64/scale;
    double sAl = sA[lane];
    double azc = (lane==0) ? fma(sAl, Pa, -sA[64]*P64) : (-sAl*Pa);
    double az = wsumd(azc);
    double dz = acosh(fmax(az, 1.0+EPS_));
    double uza  = fma(az, sAl,    Pa);
    double uz64 = fma(az, sA[64], P64);
    double c4v = (lane==0) ? fma(uz64,uz64, -uza*uza) : uza*uza;
    double mz = wsumd(c4v);
    double unz = sqrt(fmax(mz, TINY_));
    double fz = dz/fmax(unz, TINY_);
    float* Zr = Z + (size_t)(i0+r)*HA_ + h*A_;
    Zr[lane] = (float)(fz*uza);
    if (lane==0) Zr[64] = (float)(fz*uz64);
  }
}

// ---------------- kernel 3: out = Z @ Wo + bo (f32)
__global__ __launch_bounds__(256) void k_outD(
    const float* __restrict__ Zb, const float* __restrict__ Wo,
    const float* __restrict__ bo, float* __restrict__ out){
  int c  = blockIdx.x*256 + threadIdx.x;
  int t0 = blockIdx.y*CTT;
  float acc[CTT];
#pragma unroll
  for (int i=0;i<CTT;i++) acc[i]=0.f;
  for (int k=0;k<HA_;k+=4){
    float w0 = Wo[(size_t)(k+0)*D_ + c];
    float w1 = Wo[(size_t)(k+1)*D_ + c];
    float w2 = Wo[(size_t)(k+2)*D_ + c];
    float w3 = Wo[(size_t)(k+3)*D_ + c];
#pragma unroll
    for (int i=0;i<CTT;i++){
      const float* zr = Zb + (size_t)(t0+i)*HA_;
      acc[i] = fmaf(zr[k+0], w0, acc[i]);
      acc[i] = fmaf(zr[k+1], w1, acc[i]);
      acc[i] = fmaf(zr[k+2], w2, acc[i]);
      acc[i] = fmaf(zr[k+3], w3, acc[i]);
    }
  }
  float bb = bo[c];
#pragma unroll
  for (int i=0;i<CTT;i++) out[(t0+i)*D_ + c] = acc[i] + bb;
}

extern "C" void kernel_launch(void* const* d_in, const int* in_sizes, int n_in,
                              void* d_out, int out_size, void* d_ws, size_t ws_size,
                              hipStream_t stream){
  float* out = (float*)d_out;

  bool ok = (n_in == 10) && (out_size == T_*D_)
    && in_sizes[0]==T_*D_ && in_sizes[1]==D_*HN_ && in_sizes[2]==HN_
    && in_sizes[3]==D_*HN_ && in_sizes[4]==HN_
    && in_sizes[5]==D_*HN_ && in_sizes[6]==HN_
    && in_sizes[7]==HA_*D_ && in_sizes[8]==D_ && in_sizes[9]==A_;
  if (!ok){ k_fill<<<1024,256,0,stream>>>(out, 1.0e12f); return; }

  const float* x      = (const float*)d_in[0];
  const float* Wq     = (const float*)d_in[1];
  const float* bq     = (const float*)d_in[2];
  const float* Wk     = (const float*)d_in[3];
  const float* bk     = (const float*)d_in[4];
  const float* Wv     = (const float*)d_in[5];
  const float* bv     = (const float*)d_in[6];
  const float* Wo     = (const float*)d_in[7];
  const float* bo     = (const float*)d_in[8];
  const float* anchor = (const float*)d_in[9];
  char* ws = (char*)d_ws;

  size_t zbytes  = (size_t)T_*HA_*sizeof(float);            // 1,064,960
  size_t qbytes  = (size_t)H_*T_*QS_*sizeof(double);        // 2,162,688
  size_t ktbytes = (size_t)H_*66*KTS_*sizeof(float);        // 1,081,344
  size_t vbytes  = (size_t)H_*T_*VS_*sizeof(float);         // 1,081,344
  size_t vtbytes = (size_t)H_*66*KTS_*sizeof(float);        // 1,081,344
  size_t need    = zbytes+qbytes+ktbytes+vbytes+vtbytes;    // 6,471,680 <= proven 7,569,408
  if (ws_size < need){ k_fill<<<1024,256,0,stream>>>(out, 2.0e12f); return; }

  float*  Zf = (float*)ws;
  double* Qd = (double*)(ws + zbytes);
  float*  KT = (float*) (ws + zbytes + qbytes);
  float*  Vf = (float*) (ws + zbytes + qbytes + ktbytes);
  float*  VT = (float*) (ws + zbytes + qbytes + ktbytes + vbytes);

  k_projlift<<<dim3(2,3,T_/PTT), 256, 0, stream>>>(x, Wq,bq, Wk,bk, Wv,bv, Qd, KT, Vf, VT);
  k_attnF   <<<dim3(H_, T_/IT),  256, 0, stream>>>(Qd, KT, VT, Vf, anchor, Zf);
  k_outD    <<<dim3(2, T_/CTT),  256, 0, stream>>>(Zf, Wo, bo, out);
}